// Round 3
// baseline (566.821 us; speedup 1.0000x reference)
//
#include <hip/hip_runtime.h>
#include <math.h>

#define D_DIM 1024
#define MAX_TILES 40   // worst-case sum of ceil(cnt_e/128) = 32 + 7 < 40

typedef __attribute__((ext_vector_type(4))) float f32x4;
typedef __attribute__((ext_vector_type(8))) short s16x8;

__device__ __forceinline__ unsigned short f2bf(float f){
  union { float f; unsigned u; } v; v.f = f;
  unsigned r = v.u + 0x7FFFu + ((v.u >> 16) & 1u);   // RNE; inputs finite
  return (unsigned short)(r >> 16);
}

__device__ __forceinline__ void gld_lds16(const unsigned short* g, unsigned short* l){
  __builtin_amdgcn_global_load_lds(
      (const __attribute__((address_space(1))) unsigned int*)g,
      (__attribute__((address_space(3))) unsigned int*)l, 16, 0, 0);
}

// ---------------- router body: fp64 logits, argmax, w_t, aux-loss sums ----------------
__device__ __forceinline__ void router_body(
    const float* __restrict__ x, const float* __restrict__ gumbel,
    const float* __restrict__ rw, const float* __restrict__ rb,
    int* __restrict__ expert_id, float* __restrict__ wtok,
    double* __restrict__ prob_sums, int* __restrict__ counts,
    int rb_idx, float* sprob /* 4*8 floats */)
{
  int wave = threadIdx.x >> 6, lane = threadIdx.x & 63;
  int t = rb_idx * 4 + wave;
  const float* xr = x + (size_t)t * D_DIM;
  double acc[8];
  #pragma unroll
  for (int e = 0; e < 8; e++) acc[e] = 0.0;
  #pragma unroll
  for (int i = 0; i < 16; i++){
    int d = i * 64 + lane;
    double xv = (double)xr[d];
    const float4* rwp = (const float4*)(rw + (size_t)d * 8);
    float4 r0 = rwp[0], r1 = rwp[1];
    acc[0] += xv * (double)r0.x; acc[1] += xv * (double)r0.y;
    acc[2] += xv * (double)r0.z; acc[3] += xv * (double)r0.w;
    acc[4] += xv * (double)r1.x; acc[5] += xv * (double)r1.y;
    acc[6] += xv * (double)r1.z; acc[7] += xv * (double)r1.w;
  }
  #pragma unroll
  for (int e = 0; e < 8; e++){
    #pragma unroll
    for (int off = 32; off; off >>= 1) acc[e] += __shfl_xor(acc[e], off);
  }
  double logit[8], z[8];
  #pragma unroll
  for (int e = 0; e < 8; e++){
    logit[e] = acc[e] + (double)rb[e];
    z[e] = logit[e] + (double)gumbel[(size_t)t * 8 + e];
  }
  int amax = 0;
  #pragma unroll
  for (int e = 1; e < 8; e++) if (z[e] > z[amax]) amax = e;   // first-max like jnp.argmax
  float zm = (float)z[amax];
  float se = 0.f;
  #pragma unroll
  for (int e = 0; e < 8; e++) se += expf((float)z[e] - zm);
  float y = 1.f / se;                 // y_soft at argmax
  float w = (1.0f - y) + y;           // replicate ref fp32 arithmetic
  double lm = logit[0];
  #pragma unroll
  for (int e = 1; e < 8; e++) lm = fmax(lm, logit[e]);
  float p[8]; float ps = 0.f;
  #pragma unroll
  for (int e = 0; e < 8; e++){ p[e] = expf((float)(logit[e] - lm)); ps += p[e]; }
  float inv = 1.f / ps;

  if (lane == 0){
    expert_id[t] = amax; wtok[t] = w;
    atomicAdd(&counts[amax], 1);
    #pragma unroll
    for (int e = 0; e < 8; e++) sprob[wave * 8 + e] = p[e] * inv;
  }
  __syncthreads();
  if (threadIdx.x < 8){
    double s = (double)sprob[0 * 8 + threadIdx.x] + (double)sprob[1 * 8 + threadIdx.x]
             + (double)sprob[2 * 8 + threadIdx.x] + (double)sprob[3 * 8 + threadIdx.x];
    atomicAdd(&prob_sums[threadIdx.x], s);
  }
}

// ---------------- weight transpose body: fp32 [K][N] tile -> bf16 [N][K] ----------------
__device__ __forceinline__ void transpose_body(
    const float* __restrict__ W, unsigned short* __restrict__ WT,
    int K, int N, int kx, int ny, int e, float* tile /* 64*65 floats */)
{
  int k0 = kx * 64;
  int n0 = ny * 64;
  const float* src = W + (size_t)e * K * N;
  int tid = threadIdx.x;
  int r = tid >> 4;              // 0..15
  int c4 = (tid & 15) * 4;       // 0..60
  #pragma unroll
  for (int j = 0; j < 4; j++){
    int k = r + j * 16;
    float4 v = *(const float4*)(src + (size_t)(k0 + k) * N + n0 + c4);
    tile[k * 65 + c4] = v.x; tile[k * 65 + c4 + 1] = v.y;
    tile[k * 65 + c4 + 2] = v.z; tile[k * 65 + c4 + 3] = v.w;
  }
  __syncthreads();
  unsigned short* dst = WT + (size_t)e * N * K;
  #pragma unroll
  for (int it = 0; it < 2; it++){
    int idx = it * 256 + tid;
    int n = idx >> 3;            // 0..63
    int s = idx & 7;             // 16B k-segment
    unsigned short buf[8];
    #pragma unroll
    for (int j = 0; j < 8; j++) buf[j] = f2bf(tile[(s * 8 + j) * 65 + n]);
    *(s16x8*)(dst + (size_t)(n0 + n) * K + k0 + s * 8) = *(s16x8*)buf;
  }
}

// ---------------- mega-kernel A: transpose(w1) || router (independent) ----------------
__global__ __launch_bounds__(256) void stage_a(
    const float* __restrict__ w1, unsigned short* __restrict__ wT1,
    const float* __restrict__ x, const float* __restrict__ gumbel,
    const float* __restrict__ rw, const float* __restrict__ rb,
    int* __restrict__ expert_id, float* __restrict__ wtok,
    double* __restrict__ prob_sums, int* __restrict__ counts)
{
  __shared__ float smem[64 * 65];
  int b = blockIdx.x;
  if (b < 8192){
    // w1: [8][1024][4096] -> [8][4096][1024]; grid (16 kx, 64 ny, 8 e) flattened
    transpose_body(w1, wT1, 1024, 4096, b & 15, (b >> 4) & 63, b >> 10, smem);
  } else {
    router_body(x, gumbel, rw, rb, expert_id, wtok, prob_sums, counts, b - 8192, smem);
  }
}

// ---------------- finalize: offsets/cursors + flattened 128-row tile list + aux loss ----------------
__global__ void finalize_kernel(const double* __restrict__ prob_sums, const int* __restrict__ counts,
                                int* __restrict__ offsets, int* __restrict__ cursor,
                                int* __restrict__ tile_e, int* __restrict__ tile_start,
                                int* __restrict__ tile_rows, int* __restrict__ n_mtiles,
                                float* __restrict__ aux_out)
{
  if (threadIdx.x == 0){
    int off = 0, m = 0;
    for (int e = 0; e < 8; e++){
      offsets[e] = off; cursor[e] = off;
      int c = counts[e];
      for (int by = 0; by * 128 < c; by++){
        tile_e[m] = e;
        tile_start[m] = off + by * 128;
        int r = c - by * 128;
        tile_rows[m] = r < 128 ? r : 128;
        m++;
      }
      off += c;
    }
    n_mtiles[0] = m;
    double aux = 0.0;
    for (int e = 0; e < 8; e++){
      double d = prob_sums[e] / 4096.0 - 0.125;
      aux += d * d;
    }
    aux_out[0] = (float)(aux / 8.0);
  }
}

// ---------------- mega-kernel B: transpose(w2) || scatter (independent) ----------------
__global__ __launch_bounds__(256) void stage_b(
    const float* __restrict__ w2, unsigned short* __restrict__ wT2,
    const float* __restrict__ x, const int* __restrict__ expert_id,
    const float* __restrict__ wtok, int* __restrict__ cursor,
    int* __restrict__ token_of, float* __restrict__ gw,
    unsigned short* __restrict__ Xg)
{
  __shared__ float smem[64 * 65];
  int b = blockIdx.x;
  if (b < 8192){
    // w2: [8][4096][1024] -> [8][1024][4096]; grid (64 kx, 16 ny, 8 e) flattened
    transpose_body(w2, wT2, 4096, 1024, b & 63, (b >> 6) & 15, b >> 10, smem);
  } else {
    int t = b - 8192;
    int* spos = (int*)smem;
    if (threadIdx.x == 0){
      int e = expert_id[t];
      int p = atomicAdd(&cursor[e], 1);
      spos[0] = p;
      token_of[p] = t; gw[p] = wtok[t];
    }
    __syncthreads();
    int pos = spos[0];
    float4 v = ((const float4*)(x + (size_t)t * D_DIM))[threadIdx.x];
    ushort4 o; o.x = f2bf(v.x); o.y = f2bf(v.y); o.z = f2bf(v.z); o.w = f2bf(v.w);
    ((ushort4*)(Xg + (size_t)pos * D_DIM))[threadIdx.x] = o;
  }
}

// ---------------- grouped GEMM: counted-vmcnt dbuf + split-kh lgkmcnt interleave ----------------
// Tile 128x128, BK=64, 256 threads (2x2 waves of 64x64), mfma 16x16x32 bf16.
// Per K-step kt:
//   vmcnt(8) ; s_barrier                  -> tile kt landed; kt+1's 8 loads in flight
//   issue 16 ds_read_b128 (kh0 then kh1)
//   lgkmcnt(8) ; sched_barrier ; MFMA kh0 x16    <- covers kh1 read latency
//   lgkmcnt(0) ; sched_barrier ; s_barrier       <- buf[cur] fully read by all waves
//   issue stage(tile kt+2 -> buf[cur])   (no wait)
//   MFMA kh1 x16                                 <- covers staging issue
// LDS XOR-swizzle (16B slot ^= row&7) via pre-swizzled global source + same XOR on read.
template<int K, int N, int PASS2>
__global__ __launch_bounds__(256, 2) void ffn_gemm(
    const unsigned short* __restrict__ A,
    const unsigned short* __restrict__ BT,
    const float* __restrict__ bias,
    const int* __restrict__ tile_e, const int* __restrict__ tile_start,
    const int* __restrict__ tile_rows, const int* __restrict__ n_mtiles,
    const int* __restrict__ token_of, const float* __restrict__ gw,
    unsigned short* __restrict__ Hout,   // pass1: bf16 gelu output
    float* __restrict__ Fout)            // pass2: fp32 scattered rows, (acc+b2)*w
{
  int mt = blockIdx.y;
  if (mt >= n_mtiles[0]) return;
  int e = tile_e[mt], tstart = tile_start[mt], trows = tile_rows[mt];
  int bx = blockIdx.x;
  int tid = threadIdx.x, lane = tid & 63;
  int wv = __builtin_amdgcn_readfirstlane(tid >> 6);
  int wm = wv & 1, wn = wv >> 1;
  constexpr int NK = K / 64;

  __shared__ unsigned short sA[2][128 * 64];   // 2 x 16 KB
  __shared__ unsigned short sB[2][128 * 64];   // 2 x 16 KB

  // staging: chunk = 8 rows x 64 k = 1 KB; lane i -> row = c*8 + (i>>3),
  // physical 16B slot p = i&7 must hold logical k-seg s = p ^ (row&7).
  int r8  = lane >> 3;
  int swz = ((lane & 7) ^ r8) * 8;   // element offset of this lane's logical k-seg

  const unsigned short* ap[4]; int al[4];
  #pragma unroll
  for (int j = 0; j < 4; j++){
    int c = wv * 4 + j;                 // A chunk 0..15
    int row = c * 8 + r8;
    int rr = row < trows ? row : 0;     // clamp to a valid grouped row; masked at store
    ap[j] = A + (size_t)(tstart + rr) * K + swz;
    al[j] = c * 512;
  }
  const unsigned short* bp[4]; int bl[4];
  #pragma unroll
  for (int j = 0; j < 4; j++){
    int c = wv * 4 + j;                 // B chunk 0..15
    int n = bx * 128 + c * 8 + r8;
    bp[j] = BT + ((size_t)e * N + n) * K + swz;
    bl[j] = c * 512;
  }

  f32x4 accv[4][4];
  #pragma unroll
  for (int mi = 0; mi < 4; mi++)
    #pragma unroll
    for (int ni = 0; ni < 4; ni++) accv[mi][ni] = (f32x4){0.f, 0.f, 0.f, 0.f};

  // prologue: stage tiles 0 and 1 (16 loads outstanding per wave)
  #pragma unroll
  for (int b = 0; b < 2; b++){
    #pragma unroll
    for (int j = 0; j < 4; j++){ gld_lds16(ap[j], &sA[b][al[j]]); ap[j] += 64; }
    #pragma unroll
    for (int j = 0; j < 4; j++){ gld_lds16(bp[j], &sB[b][bl[j]]); bp[j] += 64; }
  }

  int col = lane & 15, quad = lane >> 4, rx = col & 7;
  int ps0 = (quad ^ rx) * 8;          // swizzled 16B slot, kh=0
  int ps1 = ((4 + quad) ^ rx) * 8;    // kh=1
  for (int kt = 0; kt < NK; ++kt){
    int cur = kt & 1;
    if (kt + 1 < NK) asm volatile("s_waitcnt vmcnt(8)" ::: "memory");
    else             asm volatile("s_waitcnt vmcnt(0)" ::: "memory");
    __builtin_amdgcn_sched_barrier(0);
    __builtin_amdgcn_s_barrier();       // buf[cur] visible to all waves
    s16x8 af0[4], bf0[4], af1[4], bf1[4];
    #pragma unroll
    for (int mi = 0; mi < 4; mi++)
      af0[mi] = *(const s16x8*)&sA[cur][(wm * 64 + mi * 16 + col) * 64 + ps0];
    #pragma unroll
    for (int ni = 0; ni < 4; ni++)
      bf0[ni] = *(const s16x8*)&sB[cur][(wn * 64 + ni * 16 + col) * 64 + ps0];
    #pragma unroll
    for (int mi = 0; mi < 4; mi++)
      af1[mi] = *(const s16x8*)&sA[cur][(wm * 64 + mi * 16 + col) * 64 + ps1];
    #pragma unroll
    for (int ni = 0; ni < 4; ni++)
      bf1[ni] = *(const s16x8*)&sB[cur][(wn * 64 + ni * 16 + col) * 64 + ps1];
    asm volatile("s_waitcnt lgkmcnt(8)" ::: "memory");   // kh0 fragments ready
    __builtin_amdgcn_sched_barrier(0);
    __builtin_amdgcn_s_setprio(1);
    #pragma unroll
    for (int mi = 0; mi < 4; mi++)
      #pragma unroll
      for (int ni = 0; ni < 4; ni++)
        accv[mi][ni] = __builtin_amdgcn_mfma_f32_16x16x32_bf16(af0[mi], bf0[ni], accv[mi][ni], 0, 0, 0);
    __builtin_amdgcn_s_setprio(0);
    asm volatile("s_waitcnt lgkmcnt(0)" ::: "memory");   // all 16 reads complete
    __builtin_amdgcn_sched_barrier(0);
    __builtin_amdgcn_s_barrier();       // every wave done reading buf[cur]
    if (kt + 2 < NK){                   // overwrite buf[cur] with tile kt+2 (issue only)
      #pragma unroll
      for (int j = 0; j < 4; j++){ gld_lds16(ap[j], &sA[cur][al[j]]); ap[j] += 64; }
      #pragma unroll
      for (int j = 0; j < 4; j++){ gld_lds16(bp[j], &sB[cur][bl[j]]); bp[j] += 64; }
    }
    __builtin_amdgcn_s_setprio(1);
    #pragma unroll
    for (int mi = 0; mi < 4; mi++)
      #pragma unroll
      for (int ni = 0; ni < 4; ni++)
        accv[mi][ni] = __builtin_amdgcn_mfma_f32_16x16x32_bf16(af1[mi], bf1[ni], accv[mi][ni], 0, 0, 0);
    __builtin_amdgcn_s_setprio(0);
  }

  float bv[4];
  #pragma unroll
  for (int ni = 0; ni < 4; ni++)
    bv[ni] = bias[(size_t)e * N + bx * 128 + wn * 64 + ni * 16 + col];

  if (PASS2 == 0){
    #pragma unroll
    for (int mi = 0; mi < 4; mi++){
      int rbase = wm * 64 + mi * 16 + quad * 4;
      #pragma unroll
      for (int r = 0; r < 4; r++){
        int row = rbase + r;
        if (row < trows){
          size_t orow = (size_t)(tstart + row) * N + bx * 128 + wn * 64 + col;
          #pragma unroll
          for (int ni = 0; ni < 4; ni++){
            float v = accv[mi][ni][r] + bv[ni];
            float g = 0.5f * v * (1.0f + erff(v * 0.70710678118654752f));  // exact gelu
            Hout[orow + ni * 16] = f2bf(g);
          }
        }
      }
    }
  } else {
    #pragma unroll
    for (int mi = 0; mi < 4; mi++){
      int rbase = wm * 64 + mi * 16 + quad * 4;
      #pragma unroll
      for (int r = 0; r < 4; r++){
        int row = rbase + r;
        if (row < trows){
          int pos = tstart + row;
          int tok = token_of[pos];
          float wgt = gw[pos];
          size_t orow = (size_t)tok * N + bx * 128 + wn * 64 + col;
          #pragma unroll
          for (int ni = 0; ni < 4; ni++)
            Fout[orow + ni * 16] = (accv[mi][ni][r] + bv[ni]) * wgt;
        }
      }
    }
  }
}

extern "C" void kernel_launch(void* const* d_in, const int* in_sizes, int n_in,
                              void* d_out, int out_size, void* d_ws, size_t ws_size,
                              hipStream_t stream)
{
  const float* x      = (const float*)d_in[0];
  const float* gumbel = (const float*)d_in[1];
  const float* rw     = (const float*)d_in[2];
  const float* rb     = (const float*)d_in[3];
  const float* w1     = (const float*)d_in[4];
  const float* b1     = (const float*)d_in[5];
  const float* w2     = (const float*)d_in[6];
  const float* b2     = (const float*)d_in[7];
  float* out = (float*)d_out;

  char* ws = (char*)d_ws;
  double* prob_sums = (double*)(ws + 0);        // 64 B
  int* counts     = (int*)(ws + 64);
  int* offsets    = (int*)(ws + 96);
  int* cursor     = (int*)(ws + 128);
  int* n_mtiles   = (int*)(ws + 160);
  int* tile_e     = (int*)(ws + 192);           // 48 ints
  int* tile_start = (int*)(ws + 384);
  int* tile_rows  = (int*)(ws + 576);
  int* expert_id  = (int*)(ws + 1024);                    // 16 KB
  float* wtok     = (float*)(ws + 1024 + 16384);          // 16 KB
  int* token_of   = (int*)(ws + 1024 + 2 * 16384);        // 16 KB
  float* gw       = (float*)(ws + 1024 + 3 * 16384);      // 16 KB -> ends at 66560
  unsigned short* Xg     = (unsigned short*)(ws + 66560);                        // 8 MB bf16
  unsigned short* hidden = (unsigned short*)(ws + 66560 + 8388608);              // 32 MB bf16
  unsigned short* wT1    = (unsigned short*)(ws + 66560 + 8388608 + 33554432);   // 64 MB
  unsigned short* wT2    = (unsigned short*)(ws + 66560 + 8388608 + 33554432 + 67108864); // 64 MB

  hipMemsetAsync(ws, 0, 256, stream);   // zero atomic accumulators (capture-safe)

  // transpose(w1) || router  (independent; router blocks appended after 8192 transpose blocks)
  stage_a<<<8192 + 1024, 256, 0, stream>>>(w1, wT1, x, gumbel, rw, rb,
                                           expert_id, wtok, prob_sums, counts);
  finalize_kernel<<<1, 64, 0, stream>>>(prob_sums, counts, offsets, cursor,
                                        tile_e, tile_start, tile_rows, n_mtiles, out + 4194304);
  // transpose(w2) || scatter  (scatter needs finalize's cursor; transpose2 independent)
  stage_b<<<8192 + 4096, 256, 0, stream>>>(w2, wT2, x, expert_id, wtok, cursor,
                                           token_of, gw, Xg);

  // hidden = gelu(Xg @ w1[e] + b1[e])   (M=cnt_e grouped, N=4096, K=1024)
  ffn_gemm<1024, 4096, 0><<<dim3(32, MAX_TILES), 256, 0, stream>>>(
      Xg, wT1, b1, tile_e, tile_start, tile_rows, n_mtiles, nullptr, nullptr, hidden, nullptr);

  // out[tok] = w_t * (hidden @ w2[e] + b2[e])   (M=cnt_e grouped, N=1024, K=4096)
  ffn_gemm<4096, 1024, 1><<<dim3(8, MAX_TILES), 256, 0, stream>>>(
      hidden, wT2, b2, tile_e, tile_start, tile_rows, n_mtiles, token_of, gw, nullptr, out);
}

// Round 4
// 560.835 us; speedup vs baseline: 1.0107x; 1.0107x over previous
//
#include <hip/hip_runtime.h>
#include <math.h>

#define D_DIM 1024
#define MAX_TILES 40   // worst-case sum of ceil(cnt_e/128) = 32 + 7 < 40

typedef __attribute__((ext_vector_type(4))) float f32x4;
typedef __attribute__((ext_vector_type(8))) short s16x8;

__device__ __forceinline__ unsigned short f2bf(float f){
  union { float f; unsigned u; } v; v.f = f;
  unsigned r = v.u + 0x7FFFu + ((v.u >> 16) & 1u);   // RNE; inputs finite
  return (unsigned short)(r >> 16);
}

__device__ __forceinline__ void gld_lds16(const unsigned short* g, unsigned short* l){
  __builtin_amdgcn_global_load_lds(
      (const __attribute__((address_space(1))) unsigned int*)g,
      (__attribute__((address_space(3))) unsigned int*)l, 16, 0, 0);
}

// ---------------- router: fp64 logits, argmax, w_t, aux-loss sums ----------------
__global__ __launch_bounds__(256) void router_kernel(
    const float* __restrict__ x, const float* __restrict__ gumbel,
    const float* __restrict__ rw, const float* __restrict__ rb,
    int* __restrict__ expert_id, float* __restrict__ wtok,
    double* __restrict__ prob_sums, int* __restrict__ counts)
{
  int wave = threadIdx.x >> 6, lane = threadIdx.x & 63;
  int t = blockIdx.x * 4 + wave;
  const float* xr = x + (size_t)t * D_DIM;
  double acc[8];
  #pragma unroll
  for (int e = 0; e < 8; e++) acc[e] = 0.0;
  #pragma unroll
  for (int i = 0; i < 16; i++){
    int d = i * 64 + lane;
    double xv = (double)xr[d];
    const float4* rwp = (const float4*)(rw + (size_t)d * 8);
    float4 r0 = rwp[0], r1 = rwp[1];
    acc[0] += xv * (double)r0.x; acc[1] += xv * (double)r0.y;
    acc[2] += xv * (double)r0.z; acc[3] += xv * (double)r0.w;
    acc[4] += xv * (double)r1.x; acc[5] += xv * (double)r1.y;
    acc[6] += xv * (double)r1.z; acc[7] += xv * (double)r1.w;
  }
  #pragma unroll
  for (int e = 0; e < 8; e++){
    #pragma unroll
    for (int off = 32; off; off >>= 1) acc[e] += __shfl_xor(acc[e], off);
  }
  double logit[8], z[8];
  #pragma unroll
  for (int e = 0; e < 8; e++){
    logit[e] = acc[e] + (double)rb[e];
    z[e] = logit[e] + (double)gumbel[(size_t)t * 8 + e];
  }
  int amax = 0;
  #pragma unroll
  for (int e = 1; e < 8; e++) if (z[e] > z[amax]) amax = e;   // first-max like jnp.argmax
  float zm = (float)z[amax];
  float se = 0.f;
  #pragma unroll
  for (int e = 0; e < 8; e++) se += expf((float)z[e] - zm);
  float y = 1.f / se;                 // y_soft at argmax
  float w = (1.0f - y) + y;           // replicate ref fp32 arithmetic
  double lm = logit[0];
  #pragma unroll
  for (int e = 1; e < 8; e++) lm = fmax(lm, logit[e]);
  float p[8]; float ps = 0.f;
  #pragma unroll
  for (int e = 0; e < 8; e++){ p[e] = expf((float)(logit[e] - lm)); ps += p[e]; }
  float inv = 1.f / ps;

  __shared__ float sprob[4][8];
  if (lane == 0){
    expert_id[t] = amax; wtok[t] = w;
    atomicAdd(&counts[amax], 1);
    #pragma unroll
    for (int e = 0; e < 8; e++) sprob[wave][e] = p[e] * inv;
  }
  __syncthreads();
  if (threadIdx.x < 8){
    double s = (double)sprob[0][threadIdx.x] + (double)sprob[1][threadIdx.x]
             + (double)sprob[2][threadIdx.x] + (double)sprob[3][threadIdx.x];
    atomicAdd(&prob_sums[threadIdx.x], s);
  }
}

// ---------------- finalize: offsets/cursors + flattened 128-row tile list + aux loss ----------------
__global__ void finalize_kernel(const double* __restrict__ prob_sums, const int* __restrict__ counts,
                                int* __restrict__ offsets, int* __restrict__ cursor,
                                int* __restrict__ tile_e, int* __restrict__ tile_start,
                                int* __restrict__ tile_rows, int* __restrict__ n_mtiles,
                                float* __restrict__ aux_out)
{
  if (threadIdx.x == 0){
    int off = 0, m = 0;
    for (int e = 0; e < 8; e++){
      offsets[e] = off; cursor[e] = off;
      int c = counts[e];
      for (int by = 0; by * 128 < c; by++){
        tile_e[m] = e;
        tile_start[m] = off + by * 128;
        int r = c - by * 128;
        tile_rows[m] = r < 128 ? r : 128;
        m++;
      }
      off += c;
    }
    n_mtiles[0] = m;
    double aux = 0.0;
    for (int e = 0; e < 8; e++){
      double d = prob_sums[e] / 4096.0 - 0.125;
      aux += d * d;
    }
    aux_out[0] = (float)(aux / 8.0);
  }
}

// ---------------- scatter: counting-sort tokens + x -> bf16 grouped ----------------
__global__ __launch_bounds__(256) void scatter_kernel(
    const float* __restrict__ x, const int* __restrict__ expert_id, const float* __restrict__ wtok,
    int* __restrict__ cursor, int* __restrict__ token_of, float* __restrict__ gw,
    unsigned short* __restrict__ Xg)
{
  int t = blockIdx.x;
  __shared__ int spos;
  if (threadIdx.x == 0){
    int e = expert_id[t];
    int p = atomicAdd(&cursor[e], 1);
    spos = p;
    token_of[p] = t; gw[p] = wtok[t];
  }
  __syncthreads();
  int pos = spos;
  float4 v = ((const float4*)(x + (size_t)t * D_DIM))[threadIdx.x];
  ushort4 o; o.x = f2bf(v.x); o.y = f2bf(v.y); o.z = f2bf(v.z); o.w = f2bf(v.w);
  ((ushort4*)(Xg + (size_t)pos * D_DIM))[threadIdx.x] = o;
}

// ---------------- grouped GEMM with in-kernel B transpose+convert ----------------
// C = act(A[group] @ W[e] + bias), W fp32 [K][N] consumed DIRECTLY (no transpose kernel).
// Tile 128 x BN, BK=64, 256 threads (2x2 waves), mfma 16x16x32 bf16.
// A: bf16 grouped rows, staged via global_load_lds (linear dest, pre-swizzled src,
//    logical k-seg at phys slot p of row r is p ^ (r&7)).
// B: per tile, each thread loads 8x float-CPT vectors (coalesced along N) into regs,
//    converts fp32->bf16, ds_write_b128 into sB doing the transpose; swizzle
//    slot = seg ^ (n&7) ^ ((n>>3)&7)  (<=2-way banks on write AND read, free).
// Pipeline (counted vmcnt, depth-2 both operands; per-tile 8 B-insts + 4 A-insts):
//   entry: vmcnt(12) [A(kt) landed; B(kt+1)+A(kt+1) in flight] ; s_barrier
//   issue B-loads(kt+2) -> reg set[cur]
//   ds_read kh0 frags ; lgkmcnt(0) ; MFMA kh0
//   ds_read kh1 frags
//   vmcnt(12|4) [B(kt+1) regs landed] ; convert ; ds_write -> buf[cur^1]
//   lgkmcnt(0) ; s_barrier ; issue A-gld_lds(kt+2) -> buf[cur] ; MFMA kh1
template<int K, int N, int BN, int PASS2>
__global__ __launch_bounds__(256, 2) void ffn_gemm(
    const unsigned short* __restrict__ A,
    const float* __restrict__ W,         // fp32 [E][K][N]
    const float* __restrict__ bias,
    const int* __restrict__ tile_e, const int* __restrict__ tile_start,
    const int* __restrict__ tile_rows, const int* __restrict__ n_mtiles,
    const int* __restrict__ token_of, const float* __restrict__ gw,
    unsigned short* __restrict__ Hout,   // pass1: bf16 gelu output
    float* __restrict__ Fout)            // pass2: fp32 scattered rows, (acc+b2)*w
{
  int mt = blockIdx.y;
  if (mt >= n_mtiles[0]) return;
  int e = tile_e[mt], tstart = tile_start[mt], trows = tile_rows[mt];
  int bx = blockIdx.x;
  int tid = threadIdx.x, lane = tid & 63;
  int wv = __builtin_amdgcn_readfirstlane(tid >> 6);
  int wm = wv & 1, wn = wv >> 1;
  constexpr int NI  = BN / 32;     // accumulator cols per wave /16 (4 or 2)
  constexpr int CPT = BN / 32;     // B columns per thread (4 or 2)
  constexpr int NK  = K / 64;

  __shared__ unsigned short sA[2][128 * 64];   // 2 x 16 KB
  __shared__ unsigned short sB[2][BN * 64];    // 2 x 16/8 KB

  // ---- A staging (global_load_lds): chunk = 8 rows x 64 k; lane i -> row c*8+(i>>3),
  // phys slot i&7 holds logical seg (i&7)^(i>>3).
  int r8  = lane >> 3;
  int swzA = ((lane & 7) ^ r8) * 8;
  const unsigned short* ap[4]; int al[4];
  #pragma unroll
  for (int j = 0; j < 4; j++){
    int c = wv * 4 + j;                 // A chunk 0..15
    int row = c * 8 + r8;
    int rr = row < trows ? row : 0;     // clamp; masked at store
    ap[j] = A + (size_t)(tstart + rr) * K + swzA;
    al[j] = c * 512;
  }

  // ---- B staging (reg -> LDS): thread owns columns n = bg*CPT..+CPT-1, k-seg bs.
  int bg = tid & 31;
  int bs = tid >> 5;                    // 0..7
  const float* bsrc = W + (size_t)e * K * N + (size_t)(bs * 8) * N + (size_t)bx * BN + bg * CPT;
  int bwoff[CPT];
  #pragma unroll
  for (int c = 0; c < CPT; c++){
    int n_ = bg * CPT + c;
    int slot_ = bs ^ ((n_ & 7) ^ ((n_ >> 3) & 7));
    bwoff[c] = n_ * 64 + slot_ * 8;
  }
  float rB0[8][CPT], rB1[8][CPT];

  // ---- fragment read offsets
  int col = lane & 15, quad = lane >> 4;
  int rowA[4], rowB[NI], psB0[NI], psB1[NI];
  int psA0 = (quad ^ (col & 7)) * 8;
  int psA1 = ((4 + quad) ^ (col & 7)) * 8;
  #pragma unroll
  for (int mi = 0; mi < 4; mi++) rowA[mi] = (wm * 64 + mi * 16 + col) * 64;
  #pragma unroll
  for (int ni = 0; ni < NI; ni++){
    int n_ = wn * (BN / 2) + ni * 16 + col;
    rowB[ni] = n_ * 64;
    int sw = (n_ & 7) ^ ((n_ >> 3) & 7);
    psB0[ni] = (quad ^ sw) * 8;
    psB1[ni] = ((4 + quad) ^ sw) * 8;
  }

  f32x4 accv[4][NI];
  #pragma unroll
  for (int mi = 0; mi < 4; mi++)
    #pragma unroll
    for (int ni = 0; ni < NI; ni++) accv[mi][ni] = (f32x4){0.f, 0.f, 0.f, 0.f};

#define A_ISSUE(BUF) { \
  _Pragma("unroll") for (int j = 0; j < 4; j++){ gld_lds16(ap[j], &sA[BUF][al[j]]); ap[j] += 64; } \
  __builtin_amdgcn_sched_barrier(0); }

#define B_ISSUE(RB, KT) { \
  const float* p_ = bsrc + (size_t)(KT) * 64 * N; \
  _Pragma("unroll") for (int j = 0; j < 8; j++){ \
    if constexpr (CPT == 4) *(f32x4*)&RB[j][0] = *(const f32x4*)(p_ + (size_t)j * N); \
    else                    *(float2*)&RB[j][0] = *(const float2*)(p_ + (size_t)j * N); \
  } \
  __builtin_amdgcn_sched_barrier(0); }

#define B_WRITE(RB, BUF) { \
  _Pragma("unroll") for (int c = 0; c < CPT; c++){ \
    unsigned short tw_[8]; \
    _Pragma("unroll") for (int j = 0; j < 8; j++) tw_[j] = f2bf(RB[j][c]); \
    *(s16x8*)&sB[BUF][bwoff[c]] = *(s16x8*)tw_; \
  } }

  // ---- prologue: issue order [B(0):8][A(0):4][B(1):8], land B(0), write buf0, [A(1):4]
  B_ISSUE(rB0, 0);
  A_ISSUE(0);
  B_ISSUE(rB1, 1);
  asm volatile("s_waitcnt vmcnt(12)" ::: "memory");   // B(0) landed
  __builtin_amdgcn_sched_barrier(0);
  B_WRITE(rB0, 0);
  A_ISSUE(1);                                         // outstanding: A(0)4 B(1)8 A(1)4 = 16
  asm volatile("s_waitcnt lgkmcnt(0)" ::: "memory");  // B(0) ds_writes visible
  __builtin_amdgcn_sched_barrier(0);

#define FFN_STEP(ISSUE_RB, CONS_RB, KT) { \
  const int cur_ = (KT) & 1; \
  if ((KT) + 1 < NK) { asm volatile("s_waitcnt vmcnt(12)" ::: "memory"); } \
  else               { asm volatile("s_waitcnt vmcnt(0)"  ::: "memory"); } \
  __builtin_amdgcn_sched_barrier(0); \
  __builtin_amdgcn_s_barrier(); \
  if ((KT) + 2 < NK) { B_ISSUE(ISSUE_RB, (KT) + 2); } \
  s16x8 af0[4], bf0[NI], af1[4], bf1[NI]; \
  _Pragma("unroll") for (int mi = 0; mi < 4; mi++) \
    af0[mi] = *(const s16x8*)&sA[cur_][rowA[mi] + psA0]; \
  _Pragma("unroll") for (int ni = 0; ni < NI; ni++) \
    bf0[ni] = *(const s16x8*)&sB[cur_][rowB[ni] + psB0[ni]]; \
  asm volatile("s_waitcnt lgkmcnt(0)" ::: "memory"); \
  __builtin_amdgcn_sched_barrier(0); \
  __builtin_amdgcn_s_setprio(1); \
  _Pragma("unroll") for (int mi = 0; mi < 4; mi++) \
    _Pragma("unroll") for (int ni = 0; ni < NI; ni++) \
      accv[mi][ni] = __builtin_amdgcn_mfma_f32_16x16x32_bf16(af0[mi], bf0[ni], accv[mi][ni], 0, 0, 0); \
  __builtin_amdgcn_s_setprio(0); \
  _Pragma("unroll") for (int mi = 0; mi < 4; mi++) \
    af1[mi] = *(const s16x8*)&sA[cur_][rowA[mi] + psA1]; \
  _Pragma("unroll") for (int ni = 0; ni < NI; ni++) \
    bf1[ni] = *(const s16x8*)&sB[cur_][rowB[ni] + psB1[ni]]; \
  if ((KT) + 1 < NK) { \
    if ((KT) + 2 < NK) { asm volatile("s_waitcnt vmcnt(12)" ::: "memory"); } \
    else               { asm volatile("s_waitcnt vmcnt(4)"  ::: "memory"); } \
    __builtin_amdgcn_sched_barrier(0); \
    B_WRITE(CONS_RB, cur_ ^ 1); \
  } \
  asm volatile("s_waitcnt lgkmcnt(0)" ::: "memory"); \
  __builtin_amdgcn_sched_barrier(0); \
  __builtin_amdgcn_s_barrier(); \
  if ((KT) + 2 < NK) { A_ISSUE(cur_); } \
  __builtin_amdgcn_s_setprio(1); \
  _Pragma("unroll") for (int mi = 0; mi < 4; mi++) \
    _Pragma("unroll") for (int ni = 0; ni < NI; ni++) \
      accv[mi][ni] = __builtin_amdgcn_mfma_f32_16x16x32_bf16(af1[mi], bf1[ni], accv[mi][ni], 0, 0, 0); \
  __builtin_amdgcn_s_setprio(0); \
}

  #pragma unroll 1
  for (int kt = 0; kt < NK; kt += 2){
    FFN_STEP(rB0, rB1, kt);       // even step: issue B(kt+2)->rB0, consume B(kt+1)=rB1
    FFN_STEP(rB1, rB0, kt + 1);   // odd step
  }

#undef FFN_STEP
#undef B_WRITE
#undef B_ISSUE
#undef A_ISSUE

  float bv[NI];
  #pragma unroll
  for (int ni = 0; ni < NI; ni++)
    bv[ni] = bias[(size_t)e * N + bx * BN + wn * (BN / 2) + ni * 16 + col];

  if (PASS2 == 0){
    #pragma unroll
    for (int mi = 0; mi < 4; mi++){
      int rbase = wm * 64 + mi * 16 + quad * 4;
      #pragma unroll
      for (int r = 0; r < 4; r++){
        int row = rbase + r;
        if (row < trows){
          size_t orow = (size_t)(tstart + row) * N + bx * BN + wn * (BN / 2) + col;
          #pragma unroll
          for (int ni = 0; ni < NI; ni++){
            float v = accv[mi][ni][r] + bv[ni];
            float g = 0.5f * v * (1.0f + erff(v * 0.70710678118654752f));  // exact gelu
            Hout[orow + ni * 16] = f2bf(g);
          }
        }
      }
    }
  } else {
    #pragma unroll
    for (int mi = 0; mi < 4; mi++){
      int rbase = wm * 64 + mi * 16 + quad * 4;
      #pragma unroll
      for (int r = 0; r < 4; r++){
        int row = rbase + r;
        if (row < trows){
          int pos = tstart + row;
          int tok = token_of[pos];
          float wgt = gw[pos];
          size_t orow = (size_t)tok * N + bx * BN + wn * (BN / 2) + col;
          #pragma unroll
          for (int ni = 0; ni < NI; ni++)
            Fout[orow + ni * 16] = (accv[mi][ni][r] + bv[ni]) * wgt;
        }
      }
    }
  }
}

extern "C" void kernel_launch(void* const* d_in, const int* in_sizes, int n_in,
                              void* d_out, int out_size, void* d_ws, size_t ws_size,
                              hipStream_t stream)
{
  const float* x      = (const float*)d_in[0];
  const float* gumbel = (const float*)d_in[1];
  const float* rw     = (const float*)d_in[2];
  const float* rb     = (const float*)d_in[3];
  const float* w1     = (const float*)d_in[4];
  const float* b1     = (const float*)d_in[5];
  const float* w2     = (const float*)d_in[6];
  const float* b2     = (const float*)d_in[7];
  float* out = (float*)d_out;

  char* ws = (char*)d_ws;
  double* prob_sums = (double*)(ws + 0);        // 64 B
  int* counts     = (int*)(ws + 64);
  int* offsets    = (int*)(ws + 96);
  int* cursor     = (int*)(ws + 128);
  int* n_mtiles   = (int*)(ws + 160);
  int* tile_e     = (int*)(ws + 192);           // 48 ints
  int* tile_start = (int*)(ws + 384);
  int* tile_rows  = (int*)(ws + 576);
  int* expert_id  = (int*)(ws + 1024);                    // 16 KB
  float* wtok     = (float*)(ws + 1024 + 16384);          // 16 KB
  int* token_of   = (int*)(ws + 1024 + 2 * 16384);        // 16 KB
  float* gw       = (float*)(ws + 1024 + 3 * 16384);      // 16 KB -> ends at 66560
  unsigned short* Xg     = (unsigned short*)(ws + 66560);             // 8 MB bf16
  unsigned short* hidden = (unsigned short*)(ws + 66560 + 8388608);   // 32 MB bf16

  hipMemsetAsync(ws, 0, 256, stream);   // zero atomic accumulators (capture-safe)

  router_kernel<<<1024, 256, 0, stream>>>(x, gumbel, rw, rb, expert_id, wtok, prob_sums, counts);
  finalize_kernel<<<1, 64, 0, stream>>>(prob_sums, counts, offsets, cursor,
                                        tile_e, tile_start, tile_rows, n_mtiles, out + 4194304);
  scatter_kernel<<<4096, 256, 0, stream>>>(x, expert_id, wtok, cursor, token_of, gw, Xg);

  // hidden = gelu(Xg @ w1[e] + b1[e])   (M=cnt_e grouped, N=4096, K=1024; w1 fp32 direct)
  ffn_gemm<1024, 4096, 128, 0><<<dim3(32, MAX_TILES), 256, 0, stream>>>(
      Xg, w1, b1, tile_e, tile_start, tile_rows, n_mtiles, nullptr, nullptr, hidden, nullptr);

  // out[tok] = w_t * (hidden @ w2[e] + b2[e])   (M=cnt_e grouped, N=1024, K=4096; w2 fp32 direct)
  ffn_gemm<4096, 1024, 64, 1><<<dim3(16, MAX_TILES), 256, 0, stream>>>(
      hidden, w2, b2, tile_e, tile_start, tile_rows, n_mtiles, token_of, gw, nullptr, out);
}